// Round 8
// baseline (101.583 us; speedup 1.0000x reference)
//
#include <hip/hip_runtime.h>
#include <hip/hip_fp16.h>

// out[b,o] = sum_k x[b, conn[o,k]] * w[o,k]
// B=1024, In=8192, O=8192, K=32.
//
// R8: R7 + pk software pipeline. Structure: 8 batch rows transposed in
// LDS as f16x8 (128 KiB), one ds_read_b128 serves 8 rows per gather
// (2048 gathers/CU ~= 19 us LDS-pipe floor). XCD sibling pairing
// (blockIdx i, i+8 share a batch tile -> same XCD under i%8 round-robin
// -> x staged from L2 once). NEW: pk loads double-buffered in registers
// -- jj=0's 8 loads issue BEFORE the staging loop (hidden under the
// 256 KB x read), each jj prefetches jj+1's batch at compute start
// (hidden under gathers/fmas). Removes the per-chunk L2-latency stall.
// VGPR ~110 (cur+nxt pk bufs = 64) under the 128 cap at 4 waves/SIMD.

constexpr int IN_F    = 8192;
constexpr int OUT_F   = 8192;
constexpr int KPER    = 32;
constexpr int BATCH   = 1024;
constexpr int ROWS    = 8;         // batch rows per block
constexpr int THREADS = 1024;      // 16 waves, 1 block/CU
constexpr int OHALF   = OUT_F / 2; // outputs per block
constexpr int NJJ     = OHALF / THREADS;  // 4 output chunks
constexpr size_t PK_BYTES = (size_t)OUT_F * (KPER / 4) * 16;  // 1 MiB

// pk[j][o] (j=k/4): uint4 { i0|i1<<16, i2|i3<<16, h2(w0,w1), h2(w2,w3) }
__global__ __launch_bounds__(256)
void psl_repack(const int* __restrict__ conn, const float* __restrict__ w,
                uint4* __restrict__ pk) {
    const int t = blockIdx.x * 256 + threadIdx.x;  // OUT_F * 8 threads
    const int j = t >> 13;          // 0..7
    const int o = t & (OUT_F - 1);
    const int base = o * KPER + j * 4;
    const int4   ci = *reinterpret_cast<const int4*>(conn + base);
    const float4 wj = *reinterpret_cast<const float4*>(w + base);
    uint4 v;
    v.x = (unsigned)ci.x | ((unsigned)ci.y << 16);
    v.y = (unsigned)ci.z | ((unsigned)ci.w << 16);
    __half2 w01 = __floats2half2_rn(wj.x, wj.y);
    __half2 w23 = __floats2half2_rn(wj.z, wj.w);
    v.z = *reinterpret_cast<unsigned*>(&w01);
    v.w = *reinterpret_cast<unsigned*>(&w23);
    pk[(size_t)j * OUT_F + o] = v;
}

__device__ __forceinline__ __half2 u2h2(unsigned u) {
    return __builtin_bit_cast(__half2, u);
}
__device__ __forceinline__ unsigned packh2(float a, float b) {
    __half2 h = __floats2half2_rn(a, b);
    return *reinterpret_cast<unsigned*>(&h);
}

__global__ __launch_bounds__(THREADS, 4)
void psl_main(const float* __restrict__ x, const uint4* __restrict__ pk,
              float* __restrict__ out) {
    __shared__ uint4 lds_x[IN_F];  // 128 KiB: [col] -> 8 batch rows as f16

    const int tid = threadIdx.x;
    const int i   = blockIdx.x;
    const int bt  = ((i >> 4) << 3) | (i & 7);   // batch tile (0..127)
    const int oh  = (i >> 3) & 1;                // output half
    const long b0 = (long)bt * ROWS;

    const int obase = oh * OHALF + tid;          // first output for this thread
    const uint4* pkb = pk + obase;

    // --- pk prefetch for jj=0: issued before staging, drained at barrier ---
    uint4 cur[KPER / 4];
#pragma unroll
    for (int j = 0; j < KPER / 4; ++j) cur[j] = pkb[(size_t)j * OUT_F];

    // --- stage x: 8 coalesced row reads per column, pack to f16x8, b128 write
    const float* xr = x + b0 * IN_F;
    for (int c = tid; c < IN_F; c += THREADS) {
        float r0 = xr[0 * IN_F + c];
        float r1 = xr[1 * IN_F + c];
        float r2 = xr[2 * IN_F + c];
        float r3 = xr[3 * IN_F + c];
        float r4 = xr[4 * IN_F + c];
        float r5 = xr[5 * IN_F + c];
        float r6 = xr[6 * IN_F + c];
        float r7 = xr[7 * IN_F + c];
        uint4 pkx;
        pkx.x = packh2(r0, r1);
        pkx.y = packh2(r2, r3);
        pkx.z = packh2(r4, r5);
        pkx.w = packh2(r6, r7);
        lds_x[c] = pkx;
    }
    __syncthreads();

    float* outb = out + b0 * OUT_F;

    for (int jj = 0; jj < NJJ; ++jj) {
        const int o = obase + jj * THREADS;

        // --- prefetch next chunk's pk batch (hidden under this chunk's math)
        uint4 nxt[KPER / 4];
        if (jj < NJJ - 1) {
            const uint4* np = pk + o + THREADS;
#pragma unroll
            for (int j = 0; j < KPER / 4; ++j) nxt[j] = np[(size_t)j * OUT_F];
        }

        __half2 z = __float2half2_rn(0.f);
        __half2 a01 = z, a23 = z, a45 = z, a67 = z;   // chain a
        __half2 b01 = z, b23 = z, b45 = z, b67 = z;   // chain b

#pragma unroll
        for (int j = 0; j < KPER / 4; ++j) {
            const uint4 v = cur[j];
            const unsigned i0 = v.x & 0xFFFFu, i1 = v.x >> 16;
            const unsigned i2 = v.y & 0xFFFFu, i3 = v.y >> 16;
            const uint4 g0 = lds_x[i0];
            const uint4 g1 = lds_x[i1];
            const uint4 g2 = lds_x[i2];
            const uint4 g3 = lds_x[i3];
            const __half2 w01 = u2h2(v.z), w23 = u2h2(v.w);
            const __half2 wd0 = __half2half2(__low2half(w01));
            const __half2 wd1 = __half2half2(__high2half(w01));
            const __half2 wd2 = __half2half2(__low2half(w23));
            const __half2 wd3 = __half2half2(__high2half(w23));

            a01 = __hfma2(u2h2(g0.x), wd0, a01);
            a23 = __hfma2(u2h2(g0.y), wd0, a23);
            a45 = __hfma2(u2h2(g0.z), wd0, a45);
            a67 = __hfma2(u2h2(g0.w), wd0, a67);
            b01 = __hfma2(u2h2(g1.x), wd1, b01);
            b23 = __hfma2(u2h2(g1.y), wd1, b23);
            b45 = __hfma2(u2h2(g1.z), wd1, b45);
            b67 = __hfma2(u2h2(g1.w), wd1, b67);
            a01 = __hfma2(u2h2(g2.x), wd2, a01);
            a23 = __hfma2(u2h2(g2.y), wd2, a23);
            a45 = __hfma2(u2h2(g2.z), wd2, a45);
            a67 = __hfma2(u2h2(g2.w), wd2, a67);
            b01 = __hfma2(u2h2(g3.x), wd3, b01);
            b23 = __hfma2(u2h2(g3.y), wd3, b23);
            b45 = __hfma2(u2h2(g3.z), wd3, b45);
            b67 = __hfma2(u2h2(g3.w), wd3, b67);
        }

        const float2 r01 = __half22float2(a01), s01 = __half22float2(b01);
        const float2 r23 = __half22float2(a23), s23 = __half22float2(b23);
        const float2 r45 = __half22float2(a45), s45 = __half22float2(b45);
        const float2 r67 = __half22float2(a67), s67 = __half22float2(b67);
        outb[0 * OUT_F + o] = r01.x + s01.x;
        outb[1 * OUT_F + o] = r01.y + s01.y;
        outb[2 * OUT_F + o] = r23.x + s23.x;
        outb[3 * OUT_F + o] = r23.y + s23.y;
        outb[4 * OUT_F + o] = r45.x + s45.x;
        outb[5 * OUT_F + o] = r45.y + s45.y;
        outb[6 * OUT_F + o] = r67.x + s67.x;
        outb[7 * OUT_F + o] = r67.y + s67.y;

#pragma unroll
        for (int j = 0; j < KPER / 4; ++j) cur[j] = nxt[j];
    }
}

// ---- fallback (no-ws path, R1 structure, 4 rows / 64 KiB) ----
__global__ __launch_bounds__(512, 4)
void psl_fallback(const float* __restrict__ x, const int* __restrict__ conn,
                  const float* __restrict__ w, float* __restrict__ out) {
    __shared__ uint2 lds_x[IN_F];
    const int tid = threadIdx.x;
    const int bt  = blockIdx.x >> 1;
    const int oh  = blockIdx.x & 1;
    const long b0 = (long)bt * 4;
    const float* xr0 = x + (b0 + 0) * IN_F;
    const float* xr1 = x + (b0 + 1) * IN_F;
    const float* xr2 = x + (b0 + 2) * IN_F;
    const float* xr3 = x + (b0 + 3) * IN_F;
    for (int c = tid; c < IN_F; c += 512) {
        uint2 pkx;
        pkx.x = packh2(xr0[c], xr1[c]);
        pkx.y = packh2(xr2[c], xr3[c]);
        lds_x[c] = pkx;
    }
    __syncthreads();
    float* or0 = out + (b0 + 0) * OUT_F;
    float* or1 = out + (b0 + 1) * OUT_F;
    float* or2 = out + (b0 + 2) * OUT_F;
    float* or3 = out + (b0 + 3) * OUT_F;
    const int obase = oh * OHALF;
    for (int j = 0; j < OHALF / 512; ++j) {
        const int o = obase + j * 512 + tid;
        const int4*   c4 = reinterpret_cast<const int4*>(conn + (size_t)o * KPER);
        const float4* w4 = reinterpret_cast<const float4*>(w + (size_t)o * KPER);
        float a0 = 0.f, a1 = 0.f, a2 = 0.f, a3 = 0.f;
#define GACC(IDX, WT)                                              \
        {                                                          \
            uint2 v = lds_x[(IDX)];                                \
            __half2 h01 = *reinterpret_cast<__half2*>(&v.x);       \
            __half2 h23 = *reinterpret_cast<__half2*>(&v.y);       \
            float2 f01 = __half22float2(h01);                      \
            float2 f23 = __half22float2(h23);                      \
            a0 = fmaf(f01.x, (WT), a0);                            \
            a1 = fmaf(f01.y, (WT), a1);                            \
            a2 = fmaf(f23.x, (WT), a2);                            \
            a3 = fmaf(f23.y, (WT), a3);                            \
        }
#pragma unroll
        for (int jj = 0; jj < KPER / 4; ++jj) {
            const int4   ci = c4[jj];
            const float4 wj = w4[jj];
            GACC(ci.x, wj.x);
            GACC(ci.y, wj.y);
            GACC(ci.z, wj.z);
            GACC(ci.w, wj.w);
        }
#undef GACC
        or0[o] = a0;
        or1[o] = a1;
        or2[o] = a2;
        or3[o] = a3;
    }
}

extern "C" void kernel_launch(void* const* d_in, const int* in_sizes, int n_in,
                              void* d_out, int out_size, void* d_ws, size_t ws_size,
                              hipStream_t stream) {
    const float* x    = (const float*)d_in[0];
    const int*   conn = (const int*)d_in[1];
    const float* w    = (const float*)d_in[2];
    float*       out  = (float*)d_out;

    if (ws_size >= PK_BYTES) {
        uint4* pk = (uint4*)d_ws;
        psl_repack<<<dim3(OUT_F * (KPER / 4) / 256), 256, 0, stream>>>(conn, w, pk);
        psl_main<<<dim3((BATCH / ROWS) * 2), THREADS, 0, stream>>>(x, pk, out);
    } else {
        psl_fallback<<<dim3((BATCH / 4) * 2), 512, 0, stream>>>(x, conn, w, out);
    }
}